// Round 5
// baseline (3940.614 us; speedup 1.0000x reference)
//
#include <hip/hip_runtime.h>
#include <stdint.h>

typedef uint16_t u16;
typedef uint32_t u32;
typedef unsigned long long u64;
typedef __attribute__((ext_vector_type(8))) __bf16 bf16x8;
typedef __attribute__((ext_vector_type(8))) short short8;
typedef __attribute__((ext_vector_type(4))) float floatx4;

// ---------- helpers ----------
__device__ __forceinline__ float bf2f(u16 u) {
  union { u32 i; float f; } v; v.i = ((u32)u) << 16; return v.f;
}
__device__ __forceinline__ u16 f2bf(float f) {
  union { float f; u32 i; } v; v.f = f;
  u32 i = v.i;
  return (u16)((i + 0x7FFFu + ((i >> 16) & 1u)) >> 16); // RTNE
}
__device__ __forceinline__ float sigm(float x) { return 1.f / (1.f + __expf(-x)); }
__device__ __forceinline__ float tanh_f(float x) {
  x = fminf(15.f, fmaxf(-15.f, x));
  float e = __expf(2.f * x);
  return (e - 1.f) / (e + 1.f);
}

// ---------- fp32 -> bf16 transpose: src[R][C] f32 -> dst[C][R] bf16 ----------
__global__ void transpose_f32_bf16(const float* __restrict__ src, u16* __restrict__ dst,
                                   int R, int C) {
  __shared__ u16 tile[32][33];
  int x = blockIdx.x * 32 + threadIdx.x;
#pragma unroll
  for (int j = 0; j < 4; ++j) {
    int y = blockIdx.y * 32 + threadIdx.y + j * 8;
    if (x < C && y < R) tile[threadIdx.y + j * 8][threadIdx.x] = f2bf(src[(size_t)y * C + x]);
  }
  __syncthreads();
  int x2 = blockIdx.y * 32 + threadIdx.x;
#pragma unroll
  for (int j = 0; j < 4; ++j) {
    int y2 = blockIdx.x * 32 + threadIdx.y + j * 8;
    if (x2 < R && y2 < C) dst[(size_t)y2 * R + x2] = tile[threadIdx.x][threadIdx.y + j * 8];
  }
}

// ---------- xp GEMM: C_bf16[M,N] = A_f32[M,K] @ BT_bf16[N,K]^T + bias_f32 ----------
__global__ __launch_bounds__(256) void gemm_a32_bt(
    const float* __restrict__ A, const u16* __restrict__ BT,
    const float* __restrict__ bias, u16* __restrict__ C,
    int M, int N, int K) {
  __shared__ __align__(16) u16 As[64 * 40];
  __shared__ __align__(16) u16 Bs[64 * 40];
  const int tid = threadIdx.x;
  const int wave = tid >> 6, lane = tid & 63;
  const int q4 = lane >> 4, n16 = lane & 15;
  const int mw = (wave >> 1) * 32, nw = (wave & 1) * 32;
  const int m0 = blockIdx.y * 64, n0 = blockIdx.x * 64;
  const int ldrow = tid >> 2, ldseg = (tid & 3) * 8;

  floatx4 acc[2][2] = {};
  for (int k0 = 0; k0 < K; k0 += 32) {
    const float* ap = A + (size_t)(m0 + ldrow) * K + k0 + ldseg;
    floatx4 a0 = *(const floatx4*)ap;
    floatx4 a1 = *(const floatx4*)(ap + 4);
    short8 s;
    s[0] = (short)f2bf(a0[0]); s[1] = (short)f2bf(a0[1]);
    s[2] = (short)f2bf(a0[2]); s[3] = (short)f2bf(a0[3]);
    s[4] = (short)f2bf(a1[0]); s[5] = (short)f2bf(a1[1]);
    s[6] = (short)f2bf(a1[2]); s[7] = (short)f2bf(a1[3]);
    *(short8*)(As + ldrow * 40 + ldseg) = s;
    *(short8*)(Bs + ldrow * 40 + ldseg) =
        *(const short8*)(BT + (size_t)(n0 + ldrow) * K + k0 + ldseg);
    __syncthreads();
#pragma unroll
    for (int mi = 0; mi < 2; ++mi) {
      bf16x8 a = *(const bf16x8*)(As + (mw + mi * 16 + n16) * 40 + q4 * 8);
#pragma unroll
      for (int ni = 0; ni < 2; ++ni) {
        bf16x8 b = *(const bf16x8*)(Bs + (nw + ni * 16 + n16) * 40 + q4 * 8);
        acc[mi][ni] = __builtin_amdgcn_mfma_f32_16x16x32_bf16(a, b, acc[mi][ni], 0, 0, 0);
      }
    }
    __syncthreads();
  }
#pragma unroll
  for (int mi = 0; mi < 2; ++mi)
#pragma unroll
    for (int ni = 0; ni < 2; ++ni) {
      int col = n0 + nw + ni * 16 + n16;
      float bv = bias[col];
#pragma unroll
      for (int r = 0; r < 4; ++r) {
        int m = m0 + mw + mi * 16 + q4 * 4 + r;
        C[(size_t)m * N + col] = f2bf(acc[mi][ni][r] + bv);
      }
    }
}

// ---------- final GEMM over permuted hidden layout ----------
// A'[32768][512] row m: g=m>>13, t=(m&8191)>>4, r=m&15; output row=(g*16+r)*512+t
__global__ __launch_bounds__(256) void gemm_bt_f32out_perm(
    const u16* __restrict__ A, const u16* __restrict__ BT,
    const float* __restrict__ bias, float* __restrict__ C,
    int M, int N, int K) {
  __shared__ __align__(16) u16 As[64 * 40];
  __shared__ __align__(16) u16 Bs[64 * 40];
  const int tid = threadIdx.x;
  const int wave = tid >> 6, lane = tid & 63;
  const int q4 = lane >> 4, n16 = lane & 15;
  const int mw = (wave >> 1) * 32, nw = (wave & 1) * 32;
  const int m0 = blockIdx.y * 64, n0 = blockIdx.x * 64;
  const int ldrow = tid >> 2, ldseg = (tid & 3) * 8;

  floatx4 acc[2][2] = {};
  for (int k0 = 0; k0 < K; k0 += 32) {
    *(short8*)(As + ldrow * 40 + ldseg) =
        *(const short8*)(A + (size_t)(m0 + ldrow) * K + k0 + ldseg);
    *(short8*)(Bs + ldrow * 40 + ldseg) =
        *(const short8*)(BT + (size_t)(n0 + ldrow) * K + k0 + ldseg);
    __syncthreads();
#pragma unroll
    for (int mi = 0; mi < 2; ++mi) {
      bf16x8 a = *(const bf16x8*)(As + (mw + mi * 16 + n16) * 40 + q4 * 8);
#pragma unroll
      for (int ni = 0; ni < 2; ++ni) {
        bf16x8 b = *(const bf16x8*)(Bs + (nw + ni * 16 + n16) * 40 + q4 * 8);
        acc[mi][ni] = __builtin_amdgcn_mfma_f32_16x16x32_bf16(a, b, acc[mi][ni], 0, 0, 0);
      }
    }
    __syncthreads();
  }
#pragma unroll
  for (int mi = 0; mi < 2; ++mi)
#pragma unroll
    for (int ni = 0; ni < 2; ++ni) {
      int col = n0 + nw + ni * 16 + n16;
      float bv = bias[col];
#pragma unroll
      for (int r = 0; r < 4; ++r) {
        int m = m0 + mw + mi * 16 + q4 * 4 + r;
        int orow = ((m >> 13) * 16 + (m & 15)) * 512 + ((m & 8191) >> 4);
        C[(size_t)orow * N + col] = acc[mi][ni][r] + bv;
      }
    }
}

// ---------- LSTM scan — barrier-free per-wave chains ----------
// 32 blocks x 256 threads = 128 waves; 4 groups x 32 producer/consumer waves.
// No __syncthreads in the K-loop. Sync per step:
//   producer wave: 64 u64 relaxed-agent h stores -> s_waitcnt vmcnt(0) ->
//                  store own monotonic flag bar[g][p] = t+1 (512 B total flags)
//   consumer wave: all-64-lane poll of the 16 packed u64 flag words until
//                  every u32 >= t, then 32 relaxed-agent u64 loads = exact
//                  MFMA A-fragments (no LDS round trip).
#define T_STEPS 512
__global__ __launch_bounds__(256, 1) void lstm_scan(
    const u16* __restrict__ xp,     // [64, 512, 2048] bf16
    const u16* __restrict__ UT,     // [2048, 512] bf16
    u16* __restrict__ hT_all,       // [4][512][16][512] bf16 (also final hidden seq)
    u32* __restrict__ bar,          // [4][32] monotonic flags
    float* __restrict__ out_hT,     // [64,512] f32
    float* __restrict__ out_cT) {   // [64,512] f32
  const int bi = blockIdx.x;
  const int g = (bi & 7) >> 1;
  const int wgi = ((bi & 1) << 2) | (bi >> 3);
  const int tid = threadIdx.x;
  const int wave = tid >> 6;
  const int lane = tid & 63;
  const int n = lane & 15;
  const int q4 = lane >> 4;
  const int cb = wgi * 64 + wave * 16;   // wave's h-col base
  const int p = wgi * 4 + wave;          // producer index in group, 0..31

  __shared__ __align__(8) u16 hstw[4 * 256];  // per-wave 16x16 transpose patch
  u16* hp = hstw + wave * 256;

  // Preload U fragments (B-operand layout)
  bf16x8 u[4][16];
#pragma unroll
  for (int qg = 0; qg < 4; ++qg) {
    const u16* up = UT + (size_t)(qg * 512 + cb + n) * 512;
#pragma unroll
    for (int kt = 0; kt < 16; ++kt)
      u[qg][kt] = *(const bf16x8*)(up + kt * 32 + q4 * 8);
  }

  float cst[4] = {0.f, 0.f, 0.f, 0.f};
  const u16* xp_base = xp + (size_t)(g * 16) * T_STEPS * 2048;
  const u64* fw = (const u64*)(bar) + g * 16 + (lane & 15); // this lane's flag word
  const int hb64 = n * 128 + q4 * 2;   // lane's A-frag u64 base within an h slot

#pragma unroll 1
  for (int t = 0; t < T_STEPS; ++t) {
    // xp loads: independent of h_{t-1}; issue before the wait
    float xpv[4][4];
#pragma unroll
    for (int qg = 0; qg < 4; ++qg)
#pragma unroll
      for (int r = 0; r < 4; ++r)
        xpv[qg][r] = bf2f(xp_base[((size_t)(q4 * 4 + r) * T_STEPS + t) * 2048
                                  + qg * 512 + cb + n]);
    __asm__ volatile("" ::: "memory");

    floatx4 acc[4] = {};
    if (t > 0) {
      // all-lane ballot poll: every producer flag of this group >= t
      const u32 tv = (u32)t;
      for (;;) {
        u64 v = __hip_atomic_load(fw, __ATOMIC_RELAXED, __HIP_MEMORY_SCOPE_AGENT);
        int ok = ((u32)v >= tv) && ((u32)(v >> 32) >= tv);
        if (__all(ok)) break;
      }
      __asm__ volatile("" ::: "memory");

      // A-fragments straight from global h slot t-1 (relaxed agent u64)
      const u64* hsrc = (const u64*)(hT_all) + (size_t)(g * T_STEPS + (t - 1)) * 2048;
      u64 hq[32];
#pragma unroll
      for (int kt = 0; kt < 16; ++kt) {
        hq[2 * kt]     = __hip_atomic_load(hsrc + hb64 + kt * 8,
                                           __ATOMIC_RELAXED, __HIP_MEMORY_SCOPE_AGENT);
        hq[2 * kt + 1] = __hip_atomic_load(hsrc + hb64 + kt * 8 + 1,
                                           __ATOMIC_RELAXED, __HIP_MEMORY_SCOPE_AGENT);
      }
#pragma unroll
      for (int kt = 0; kt < 16; ++kt) {
        union { u64 q[2]; bf16x8 v; } a;
        a.q[0] = hq[2 * kt]; a.q[1] = hq[2 * kt + 1];
        acc[0] = __builtin_amdgcn_mfma_f32_16x16x32_bf16(a.v, u[0][kt], acc[0], 0, 0, 0);
        acc[1] = __builtin_amdgcn_mfma_f32_16x16x32_bf16(a.v, u[1][kt], acc[1], 0, 0, 0);
        acc[2] = __builtin_amdgcn_mfma_f32_16x16x32_bf16(a.v, u[2][kt], acc[2], 0, 0, 0);
        acc[3] = __builtin_amdgcn_mfma_f32_16x16x32_bf16(a.v, u[3][kt], acc[3], 0, 0, 0);
      }
    }

    // gates + state update (C-layout: row=q4*4+r, col=n within wave tile)
#pragma unroll
    for (int r = 0; r < 4; ++r) {
      float gi = sigm(acc[0][r] + xpv[0][r]);
      float gf = sigm(acc[1][r] + xpv[1][r]);
      float gg = tanh_f(acc[2][r] + xpv[2][r]);
      float go = sigm(acc[3][r] + xpv[3][r]);
      float cn = gf * cst[r] + gi * gg;
      cst[r] = cn;
      float hv = go * tanh_f(cn);
      int row = q4 * 4 + r;
      hp[row * 16 + n] = f2bf(hv);    // wave-private LDS transpose patch
      if (t == T_STEPS - 1) {
        out_hT[(g * 16 + row) * 512 + cb + n] = hv;
        out_cT[(g * 16 + row) * 512 + cb + n] = cn;
      }
    }
    __asm__ volatile("s_waitcnt lgkmcnt(0)" ::: "memory"); // patch visible wave-wide

    // store own 16x16 tile row-major: 1 u64 per lane, relaxed agent
    {
      int row = lane >> 2, seg = lane & 3;
      u64 v = *(const u64*)(hp + row * 16 + seg * 4);
      u64* hdst = (u64*)(hT_all) + (size_t)(g * T_STEPS + t) * 2048
                  + row * 128 + (cb >> 2) + seg;
      __hip_atomic_store(hdst, v, __ATOMIC_RELAXED, __HIP_MEMORY_SCOPE_AGENT);
    }
    __asm__ volatile("s_waitcnt vmcnt(0)" ::: "memory");   // h stores at coherence point
    if (lane == 0)
      __hip_atomic_store((u32*)bar + g * 32 + p, (u32)(t + 1),
                         __ATOMIC_RELAXED, __HIP_MEMORY_SCOPE_AGENT);
  }
}

// ---------- launch ----------
extern "C" void kernel_launch(void* const* d_in, const int* in_sizes, int n_in,
                              void* d_out, int out_size, void* d_ws, size_t ws_size,
                              hipStream_t stream) {
  (void)in_sizes; (void)n_in; (void)out_size; (void)ws_size;
  const float* x    = (const float*)d_in[0]; // [64,512,256] f32
  const float* W    = (const float*)d_in[1]; // [256,2048] f32
  const float* U    = (const float*)d_in[2]; // [512,2048] f32
  const float* bias = (const float*)d_in[3]; // [2048] f32
  const float* Wl   = (const float*)d_in[4]; // [512,256] f32
  const float* bl   = (const float*)d_in[5]; // [256] f32
  float* out = (float*)d_out;                // [64,512,256] ++ hT[64,512] ++ cT[64,512]
  char* ws = (char*)d_ws;

  u16* xp     = (u16*)(ws + 0);            // 134,217,728 B
  u16* UT     = (u16*)(ws + 134217728);    //   2,097,152 B
  u16* WT     = (u16*)(ws + 136314880);    //   1,048,576 B
  u16* WlT    = (u16*)(ws + 137363456);    //     262,144 B
  u16* hT_all = (u16*)(ws + 137625600);    //  33,554,432 B  [4][512][16][512]
  u32* bar    = (u32*)(ws + 171180032);    //         512 B  [4][32]

  hipMemsetAsync(bar, 0, 4 * 32 * sizeof(u32), stream);

  transpose_f32_bf16<<<dim3(2048 / 32, 256 / 32), dim3(32, 8), 0, stream>>>(W, WT, 256, 2048);
  transpose_f32_bf16<<<dim3(2048 / 32, 512 / 32), dim3(32, 8), 0, stream>>>(U, UT, 512, 2048);
  transpose_f32_bf16<<<dim3(256 / 32, 512 / 32), dim3(32, 8), 0, stream>>>(Wl, WlT, 512, 256);

  // x_proj = x @ W + bias : [32768,256] x [256,2048] -> bf16
  gemm_a32_bt<<<dim3(2048 / 64, 32768 / 64), 256, 0, stream>>>(x, WT, bias, xp, 32768, 2048, 256);

  // sequential LSTM scan (writes hT_all in [g][t][r][col] layout)
  lstm_scan<<<32, 256, 0, stream>>>(xp, UT, hT_all, bar,
                                    out + 8388608, out + 8421376);

  // out = hseq @ Wl + bl, reading permuted layout, remapping output rows
  gemm_bt_f32out_perm<<<dim3(256 / 64, 32768 / 64), 256, 0, stream>>>(
      hT_all, WlT, bl, out, 32768, 256, 512);
}

// Round 6
// 3097.240 us; speedup vs baseline: 1.2723x; 1.2723x over previous
//
#include <hip/hip_runtime.h>
#include <stdint.h>

typedef uint16_t u16;
typedef uint32_t u32;
typedef unsigned long long u64;
typedef __attribute__((ext_vector_type(8))) __bf16 bf16x8;
typedef __attribute__((ext_vector_type(8))) short short8;
typedef __attribute__((ext_vector_type(4))) float floatx4;

// ---------- helpers ----------
__device__ __forceinline__ float bf2f(u16 u) {
  union { u32 i; float f; } v; v.i = ((u32)u) << 16; return v.f;
}
__device__ __forceinline__ u16 f2bf(float f) {
  union { float f; u32 i; } v; v.f = f;
  u32 i = v.i;
  return (u16)((i + 0x7FFFu + ((i >> 16) & 1u)) >> 16); // RTNE
}
__device__ __forceinline__ float sigm(float x) { return 1.f / (1.f + __expf(-x)); }
__device__ __forceinline__ float tanh_f(float x) {
  x = fminf(15.f, fmaxf(-15.f, x));
  float e = __expf(2.f * x);
  return (e - 1.f) / (e + 1.f);
}

// ---------- fp32 -> bf16 transpose: src[R][C] f32 -> dst[C][R] bf16 ----------
__global__ void transpose_f32_bf16(const float* __restrict__ src, u16* __restrict__ dst,
                                   int R, int C) {
  __shared__ u16 tile[32][33];
  int x = blockIdx.x * 32 + threadIdx.x;
#pragma unroll
  for (int j = 0; j < 4; ++j) {
    int y = blockIdx.y * 32 + threadIdx.y + j * 8;
    if (x < C && y < R) tile[threadIdx.y + j * 8][threadIdx.x] = f2bf(src[(size_t)y * C + x]);
  }
  __syncthreads();
  int x2 = blockIdx.y * 32 + threadIdx.x;
#pragma unroll
  for (int j = 0; j < 4; ++j) {
    int y2 = blockIdx.x * 32 + threadIdx.y + j * 8;
    if (x2 < R && y2 < C) dst[(size_t)y2 * R + x2] = tile[threadIdx.x][threadIdx.y + j * 8];
  }
}

// ---------- xp GEMM: C_bf16[M,N] = A_f32[M,K] @ BT_bf16[N,K]^T + bias_f32 ----------
__global__ __launch_bounds__(256) void gemm_a32_bt(
    const float* __restrict__ A, const u16* __restrict__ BT,
    const float* __restrict__ bias, u16* __restrict__ C,
    int M, int N, int K) {
  __shared__ __align__(16) u16 As[64 * 40];
  __shared__ __align__(16) u16 Bs[64 * 40];
  const int tid = threadIdx.x;
  const int wave = tid >> 6, lane = tid & 63;
  const int q4 = lane >> 4, n16 = lane & 15;
  const int mw = (wave >> 1) * 32, nw = (wave & 1) * 32;
  const int m0 = blockIdx.y * 64, n0 = blockIdx.x * 64;
  const int ldrow = tid >> 2, ldseg = (tid & 3) * 8;

  floatx4 acc[2][2] = {};
  for (int k0 = 0; k0 < K; k0 += 32) {
    const float* ap = A + (size_t)(m0 + ldrow) * K + k0 + ldseg;
    floatx4 a0 = *(const floatx4*)ap;
    floatx4 a1 = *(const floatx4*)(ap + 4);
    short8 s;
    s[0] = (short)f2bf(a0[0]); s[1] = (short)f2bf(a0[1]);
    s[2] = (short)f2bf(a0[2]); s[3] = (short)f2bf(a0[3]);
    s[4] = (short)f2bf(a1[0]); s[5] = (short)f2bf(a1[1]);
    s[6] = (short)f2bf(a1[2]); s[7] = (short)f2bf(a1[3]);
    *(short8*)(As + ldrow * 40 + ldseg) = s;
    *(short8*)(Bs + ldrow * 40 + ldseg) =
        *(const short8*)(BT + (size_t)(n0 + ldrow) * K + k0 + ldseg);
    __syncthreads();
#pragma unroll
    for (int mi = 0; mi < 2; ++mi) {
      bf16x8 a = *(const bf16x8*)(As + (mw + mi * 16 + n16) * 40 + q4 * 8);
#pragma unroll
      for (int ni = 0; ni < 2; ++ni) {
        bf16x8 b = *(const bf16x8*)(Bs + (nw + ni * 16 + n16) * 40 + q4 * 8);
        acc[mi][ni] = __builtin_amdgcn_mfma_f32_16x16x32_bf16(a, b, acc[mi][ni], 0, 0, 0);
      }
    }
    __syncthreads();
  }
#pragma unroll
  for (int mi = 0; mi < 2; ++mi)
#pragma unroll
    for (int ni = 0; ni < 2; ++ni) {
      int col = n0 + nw + ni * 16 + n16;
      float bv = bias[col];
#pragma unroll
      for (int r = 0; r < 4; ++r) {
        int m = m0 + mw + mi * 16 + q4 * 4 + r;
        C[(size_t)m * N + col] = f2bf(acc[mi][ni][r] + bv);
      }
    }
}

// ---------- final GEMM over blocked+permuted hidden layout ----------
// A'row m: g=m>>13, t=(m&8191)>>4, r=m&15. Slot (g,t) = [32 tiles][16 r][16 c] u16;
// element k at (k>>4)*256 + r*16 + (k&15). Output row = (g*16+r)*512 + t.
__global__ __launch_bounds__(256) void gemm_bt_f32out_perm(
    const u16* __restrict__ A, const u16* __restrict__ BT,
    const float* __restrict__ bias, float* __restrict__ C,
    int M, int N, int K) {
  __shared__ __align__(16) u16 As[64 * 40];
  __shared__ __align__(16) u16 Bs[64 * 40];
  const int tid = threadIdx.x;
  const int wave = tid >> 6, lane = tid & 63;
  const int q4 = lane >> 4, n16 = lane & 15;
  const int mw = (wave >> 1) * 32, nw = (wave & 1) * 32;
  const int m0 = blockIdx.y * 64, n0 = blockIdx.x * 64;
  const int ldrow = tid >> 2, ldseg = (tid & 3) * 8;

  const int mm = m0 + ldrow;
  const size_t slot = ((size_t)((mm >> 13) * 512 + ((mm & 8191) >> 4))) * 8192
                      + (mm & 15) * 16;

  floatx4 acc[2][2] = {};
  for (int k0 = 0; k0 < K; k0 += 32) {
    int kk = k0 + ldseg;
    *(short8*)(As + ldrow * 40 + ldseg) =
        *(const short8*)(A + slot + (kk >> 4) * 256 + (kk & 15));
    *(short8*)(Bs + ldrow * 40 + ldseg) =
        *(const short8*)(BT + (size_t)(n0 + ldrow) * K + k0 + ldseg);
    __syncthreads();
#pragma unroll
    for (int mi = 0; mi < 2; ++mi) {
      bf16x8 a = *(const bf16x8*)(As + (mw + mi * 16 + n16) * 40 + q4 * 8);
#pragma unroll
      for (int ni = 0; ni < 2; ++ni) {
        bf16x8 b = *(const bf16x8*)(Bs + (nw + ni * 16 + n16) * 40 + q4 * 8);
        acc[mi][ni] = __builtin_amdgcn_mfma_f32_16x16x32_bf16(a, b, acc[mi][ni], 0, 0, 0);
      }
    }
    __syncthreads();
  }
#pragma unroll
  for (int mi = 0; mi < 2; ++mi)
#pragma unroll
    for (int ni = 0; ni < 2; ++ni) {
      int col = n0 + nw + ni * 16 + n16;
      float bv = bias[col];
#pragma unroll
      for (int r = 0; r < 4; ++r) {
        int m = m0 + mw + mi * 16 + q4 * 4 + r;
        int orow = ((m >> 13) * 16 + (m & 15)) * 512 + ((m & 8191) >> 4);
        C[(size_t)orow * N + col] = acc[mi][ni][r] + bv;
      }
    }
}

// ---------- LSTM scan — barrier-free per-wave chains, blocked h layout ----------
// 32 blocks x 256 threads = 128 waves; 4 groups x 32 producer waves.
// h slot (g,t) = [32 tiles][16 rows][16 cols] bf16: tile p = wave p's 16 h-cols.
//   producer: wave-private LDS transpose patch -> 512 B contiguous u64 store ->
//             s_waitcnt vmcnt(0) -> own padded flag (64 B apart) = t+1.
//   consumer: poll 32 padded flags (lane&31 -> 32 sectors, spread over slices),
//             then per ktile one dense 16 B/lane load pair = exact MFMA A-frag.
#define T_STEPS 512
__global__ __launch_bounds__(256, 1) void lstm_scan(
    const u16* __restrict__ xp,     // [64, 512, 2048] bf16
    const u16* __restrict__ UT,     // [2048, 512] bf16
    u16* __restrict__ hT_all,       // [4][512][32][16][16] bf16 (blocked hidden seq)
    u32* __restrict__ bar,          // [4][32] flags, padded x16 (64 B each)
    float* __restrict__ out_hT,     // [64,512] f32
    float* __restrict__ out_cT) {   // [64,512] f32
  const int bi = blockIdx.x;
  const int g = (bi & 7) >> 1;
  const int wgi = ((bi & 1) << 2) | (bi >> 3);
  const int tid = threadIdx.x;
  const int wave = tid >> 6;
  const int lane = tid & 63;
  const int n = lane & 15;
  const int q4 = lane >> 4;
  const int cb = wgi * 64 + wave * 16;   // wave's h-col base
  const int p = wgi * 4 + wave;          // producer/tile index in group, 0..31

  __shared__ __align__(8) u16 hstw[4 * 256];  // per-wave 16x16 transpose patch
  u16* hp = hstw + wave * 256;

  // Preload U fragments (B-operand layout)
  bf16x8 u[4][16];
#pragma unroll
  for (int qg = 0; qg < 4; ++qg) {
    const u16* up = UT + (size_t)(qg * 512 + cb + n) * 512;
#pragma unroll
    for (int kt = 0; kt < 16; ++kt)
      u[qg][kt] = *(const bf16x8*)(up + kt * 32 + q4 * 8);
  }

  float cst[4] = {0.f, 0.f, 0.f, 0.f};
  const u16* xp_base = xp + (size_t)(g * 16) * T_STEPS * 2048;
  u32* myflag = bar + (g * 32 + p) * 16;
  const u32* pollp = bar + (g * 32 + (lane & 31)) * 16;
  const int fb64 = (q4 >> 1) * 64 + n * 4 + (q4 & 1) * 2; // frag u64 offset in tile pair

#pragma unroll 1
  for (int t = 0; t < T_STEPS; ++t) {
    // xp loads: independent of h_{t-1}; issue before the wait
    float xpv[4][4];
#pragma unroll
    for (int qg = 0; qg < 4; ++qg)
#pragma unroll
      for (int r = 0; r < 4; ++r)
        xpv[qg][r] = bf2f(xp_base[((size_t)(q4 * 4 + r) * T_STEPS + t) * 2048
                                  + qg * 512 + cb + n]);
    __asm__ volatile("" ::: "memory");

    floatx4 acc[4] = {};
    if (t > 0) {
      const u32 tv = (u32)t;
      for (;;) {  // all 32 producer flags of this group >= t
        u32 v = __hip_atomic_load(pollp, __ATOMIC_RELAXED, __HIP_MEMORY_SCOPE_AGENT);
        if (__all((int)(v >= tv))) break;
      }
      __asm__ volatile("" ::: "memory");

      // A-fragments from slot t-1: dense per-ktile loads in exact MFMA layout
      const u64* hsrc = (const u64*)(hT_all) + (size_t)(g * T_STEPS + (t - 1)) * 2048 + fb64;
      u64 hq[32];
#pragma unroll
      for (int kt = 0; kt < 16; ++kt) {
        hq[2 * kt]     = __hip_atomic_load(hsrc + kt * 128,
                                           __ATOMIC_RELAXED, __HIP_MEMORY_SCOPE_AGENT);
        hq[2 * kt + 1] = __hip_atomic_load(hsrc + kt * 128 + 1,
                                           __ATOMIC_RELAXED, __HIP_MEMORY_SCOPE_AGENT);
      }
#pragma unroll
      for (int kt = 0; kt < 16; ++kt) {
        union { u64 q[2]; bf16x8 v; } a;
        a.q[0] = hq[2 * kt]; a.q[1] = hq[2 * kt + 1];
        acc[0] = __builtin_amdgcn_mfma_f32_16x16x32_bf16(a.v, u[0][kt], acc[0], 0, 0, 0);
        acc[1] = __builtin_amdgcn_mfma_f32_16x16x32_bf16(a.v, u[1][kt], acc[1], 0, 0, 0);
        acc[2] = __builtin_amdgcn_mfma_f32_16x16x32_bf16(a.v, u[2][kt], acc[2], 0, 0, 0);
        acc[3] = __builtin_amdgcn_mfma_f32_16x16x32_bf16(a.v, u[3][kt], acc[3], 0, 0, 0);
      }
    }

    // gates + state update (C-layout: row=q4*4+r, col=n within wave tile)
#pragma unroll
    for (int r = 0; r < 4; ++r) {
      float gi = sigm(acc[0][r] + xpv[0][r]);
      float gf = sigm(acc[1][r] + xpv[1][r]);
      float gg = tanh_f(acc[2][r] + xpv[2][r]);
      float go = sigm(acc[3][r] + xpv[3][r]);
      float cn = gf * cst[r] + gi * gg;
      cst[r] = cn;
      float hv = go * tanh_f(cn);
      int row = q4 * 4 + r;
      hp[row * 16 + n] = f2bf(hv);    // wave-private LDS transpose patch
      if (t == T_STEPS - 1) {
        out_hT[(g * 16 + row) * 512 + cb + n] = hv;
        out_cT[(g * 16 + row) * 512 + cb + n] = cn;
      }
    }
    __asm__ volatile("s_waitcnt lgkmcnt(0)" ::: "memory"); // patch visible wave-wide

    // store own 16x16 tile: 64 lanes x u64 = 512 B contiguous, relaxed agent
    {
      u64 v = *(const u64*)(hp + (lane >> 2) * 16 + (lane & 3) * 4);
      u64* hdst = (u64*)(hT_all) + (size_t)(g * T_STEPS + t) * 2048 + p * 64 + lane;
      __hip_atomic_store(hdst, v, __ATOMIC_RELAXED, __HIP_MEMORY_SCOPE_AGENT);
    }
    __asm__ volatile("s_waitcnt vmcnt(0)" ::: "memory");   // h stores at coherence point
    if (lane == 0)
      __hip_atomic_store(myflag, (u32)(t + 1),
                         __ATOMIC_RELAXED, __HIP_MEMORY_SCOPE_AGENT);
  }
}

// ---------- launch ----------
extern "C" void kernel_launch(void* const* d_in, const int* in_sizes, int n_in,
                              void* d_out, int out_size, void* d_ws, size_t ws_size,
                              hipStream_t stream) {
  (void)in_sizes; (void)n_in; (void)out_size; (void)ws_size;
  const float* x    = (const float*)d_in[0]; // [64,512,256] f32
  const float* W    = (const float*)d_in[1]; // [256,2048] f32
  const float* U    = (const float*)d_in[2]; // [512,2048] f32
  const float* bias = (const float*)d_in[3]; // [2048] f32
  const float* Wl   = (const float*)d_in[4]; // [512,256] f32
  const float* bl   = (const float*)d_in[5]; // [256] f32
  float* out = (float*)d_out;                // [64,512,256] ++ hT[64,512] ++ cT[64,512]
  char* ws = (char*)d_ws;

  u16* xp     = (u16*)(ws + 0);            // 134,217,728 B
  u16* UT     = (u16*)(ws + 134217728);    //   2,097,152 B
  u16* WT     = (u16*)(ws + 136314880);    //   1,048,576 B
  u16* WlT    = (u16*)(ws + 137363456);    //     262,144 B
  u16* hT_all = (u16*)(ws + 137625600);    //  33,554,432 B  [4][512][32][16][16]
  u32* bar    = (u32*)(ws + 171180032);    //       8,192 B  [4][32] x16 pad

  hipMemsetAsync(bar, 0, 4 * 32 * 16 * sizeof(u32), stream);

  transpose_f32_bf16<<<dim3(2048 / 32, 256 / 32), dim3(32, 8), 0, stream>>>(W, WT, 256, 2048);
  transpose_f32_bf16<<<dim3(2048 / 32, 512 / 32), dim3(32, 8), 0, stream>>>(U, UT, 512, 2048);
  transpose_f32_bf16<<<dim3(256 / 32, 512 / 32), dim3(32, 8), 0, stream>>>(Wl, WlT, 512, 256);

  // x_proj = x @ W + bias : [32768,256] x [256,2048] -> bf16
  gemm_a32_bt<<<dim3(2048 / 64, 32768 / 64), 256, 0, stream>>>(x, WT, bias, xp, 32768, 2048, 256);

  // sequential LSTM scan (writes hT_all in blocked [g][t][tile][row][col] layout)
  lstm_scan<<<32, 256, 0, stream>>>(xp, UT, hT_all, bar,
                                    out + 8388608, out + 8421376);

  // out = hseq @ Wl + bl, reading blocked layout, remapping output rows
  gemm_bt_f32out_perm<<<dim3(256 / 64, 32768 / 64), 256, 0, stream>>>(
      hT_all, WlT, bl, out, 32768, 256, 512);
}

// Round 7
// 2455.740 us; speedup vs baseline: 1.6047x; 1.2612x over previous
//
#include <hip/hip_runtime.h>
#include <stdint.h>

typedef uint16_t u16;
typedef uint32_t u32;
typedef unsigned long long u64;
typedef __attribute__((ext_vector_type(8))) __bf16 bf16x8;
typedef __attribute__((ext_vector_type(8))) short short8;
typedef __attribute__((ext_vector_type(4))) float floatx4;

// ---------- helpers ----------
__device__ __forceinline__ float bf2f(u16 u) {
  union { u32 i; float f; } v; v.i = ((u32)u) << 16; return v.f;
}
__device__ __forceinline__ u16 f2bf(float f) {
  union { float f; u32 i; } v; v.f = f;
  u32 i = v.i;
  return (u16)((i + 0x7FFFu + ((i >> 16) & 1u)) >> 16); // RTNE
}
__device__ __forceinline__ float sigm(float x) { return 1.f / (1.f + __expf(-x)); }
__device__ __forceinline__ float tanh_f(float x) {
  x = fminf(15.f, fmaxf(-15.f, x));
  float e = __expf(2.f * x);
  return (e - 1.f) / (e + 1.f);
}

// ---------- fp32 -> bf16 transpose: src[R][C] f32 -> dst[C][R] bf16 ----------
__global__ void transpose_f32_bf16(const float* __restrict__ src, u16* __restrict__ dst,
                                   int R, int C) {
  __shared__ u16 tile[32][33];
  int x = blockIdx.x * 32 + threadIdx.x;
#pragma unroll
  for (int j = 0; j < 4; ++j) {
    int y = blockIdx.y * 32 + threadIdx.y + j * 8;
    if (x < C && y < R) tile[threadIdx.y + j * 8][threadIdx.x] = f2bf(src[(size_t)y * C + x]);
  }
  __syncthreads();
  int x2 = blockIdx.y * 32 + threadIdx.x;
#pragma unroll
  for (int j = 0; j < 4; ++j) {
    int y2 = blockIdx.x * 32 + threadIdx.y + j * 8;
    if (x2 < R && y2 < C) dst[(size_t)y2 * R + x2] = tile[threadIdx.x][threadIdx.y + j * 8];
  }
}

// ---------- xp GEMM: C_bf16[M,N] = A_f32[M,K] @ BT_bf16[N,K]^T + bias_f32 ----------
__global__ __launch_bounds__(256) void gemm_a32_bt(
    const float* __restrict__ A, const u16* __restrict__ BT,
    const float* __restrict__ bias, u16* __restrict__ C,
    int M, int N, int K) {
  __shared__ __align__(16) u16 As[64 * 40];
  __shared__ __align__(16) u16 Bs[64 * 40];
  const int tid = threadIdx.x;
  const int wave = tid >> 6, lane = tid & 63;
  const int q4 = lane >> 4, n16 = lane & 15;
  const int mw = (wave >> 1) * 32, nw = (wave & 1) * 32;
  const int m0 = blockIdx.y * 64, n0 = blockIdx.x * 64;
  const int ldrow = tid >> 2, ldseg = (tid & 3) * 8;

  floatx4 acc[2][2] = {};
  for (int k0 = 0; k0 < K; k0 += 32) {
    const float* ap = A + (size_t)(m0 + ldrow) * K + k0 + ldseg;
    floatx4 a0 = *(const floatx4*)ap;
    floatx4 a1 = *(const floatx4*)(ap + 4);
    short8 s;
    s[0] = (short)f2bf(a0[0]); s[1] = (short)f2bf(a0[1]);
    s[2] = (short)f2bf(a0[2]); s[3] = (short)f2bf(a0[3]);
    s[4] = (short)f2bf(a1[0]); s[5] = (short)f2bf(a1[1]);
    s[6] = (short)f2bf(a1[2]); s[7] = (short)f2bf(a1[3]);
    *(short8*)(As + ldrow * 40 + ldseg) = s;
    *(short8*)(Bs + ldrow * 40 + ldseg) =
        *(const short8*)(BT + (size_t)(n0 + ldrow) * K + k0 + ldseg);
    __syncthreads();
#pragma unroll
    for (int mi = 0; mi < 2; ++mi) {
      bf16x8 a = *(const bf16x8*)(As + (mw + mi * 16 + n16) * 40 + q4 * 8);
#pragma unroll
      for (int ni = 0; ni < 2; ++ni) {
        bf16x8 b = *(const bf16x8*)(Bs + (nw + ni * 16 + n16) * 40 + q4 * 8);
        acc[mi][ni] = __builtin_amdgcn_mfma_f32_16x16x32_bf16(a, b, acc[mi][ni], 0, 0, 0);
      }
    }
    __syncthreads();
  }
#pragma unroll
  for (int mi = 0; mi < 2; ++mi)
#pragma unroll
    for (int ni = 0; ni < 2; ++ni) {
      int col = n0 + nw + ni * 16 + n16;
      float bv = bias[col];
#pragma unroll
      for (int r = 0; r < 4; ++r) {
        int m = m0 + mw + mi * 16 + q4 * 4 + r;
        C[(size_t)m * N + col] = f2bf(acc[mi][ni][r] + bv);
      }
    }
}

// ---------- final GEMM over blocked+permuted hidden layout ----------
// A'row m: g=m>>13, t=(m&8191)>>4, r=m&15. Slot (g,t) = [32 tiles][16 r][16 c] u16;
// element k at (k>>4)*256 + r*16 + (k&15). Output row = (g*16+r)*512 + t.
__global__ __launch_bounds__(256) void gemm_bt_f32out_perm(
    const u16* __restrict__ A, const u16* __restrict__ BT,
    const float* __restrict__ bias, float* __restrict__ C,
    int M, int N, int K) {
  __shared__ __align__(16) u16 As[64 * 40];
  __shared__ __align__(16) u16 Bs[64 * 40];
  const int tid = threadIdx.x;
  const int wave = tid >> 6, lane = tid & 63;
  const int q4 = lane >> 4, n16 = lane & 15;
  const int mw = (wave >> 1) * 32, nw = (wave & 1) * 32;
  const int m0 = blockIdx.y * 64, n0 = blockIdx.x * 64;
  const int ldrow = tid >> 2, ldseg = (tid & 3) * 8;

  const int mm = m0 + ldrow;
  const size_t slot = ((size_t)((mm >> 13) * 512 + ((mm & 8191) >> 4))) * 8192
                      + (mm & 15) * 16;

  floatx4 acc[2][2] = {};
  for (int k0 = 0; k0 < K; k0 += 32) {
    int kk = k0 + ldseg;
    *(short8*)(As + ldrow * 40 + ldseg) =
        *(const short8*)(A + slot + (kk >> 4) * 256 + (kk & 15));
    *(short8*)(Bs + ldrow * 40 + ldseg) =
        *(const short8*)(BT + (size_t)(n0 + ldrow) * K + k0 + ldseg);
    __syncthreads();
#pragma unroll
    for (int mi = 0; mi < 2; ++mi) {
      bf16x8 a = *(const bf16x8*)(As + (mw + mi * 16 + n16) * 40 + q4 * 8);
#pragma unroll
      for (int ni = 0; ni < 2; ++ni) {
        bf16x8 b = *(const bf16x8*)(Bs + (nw + ni * 16 + n16) * 40 + q4 * 8);
        acc[mi][ni] = __builtin_amdgcn_mfma_f32_16x16x32_bf16(a, b, acc[mi][ni], 0, 0, 0);
      }
    }
    __syncthreads();
  }
#pragma unroll
  for (int mi = 0; mi < 2; ++mi)
#pragma unroll
    for (int ni = 0; ni < 2; ++ni) {
      int col = n0 + nw + ni * 16 + n16;
      float bv = bias[col];
#pragma unroll
      for (int r = 0; r < 4; ++r) {
        int m = m0 + mw + mi * 16 + q4 * 4 + r;
        int orow = ((m >> 13) * 16 + (m & 15)) * 512 + ((m & 8191) >> 4);
        C[(size_t)orow * N + col] = acc[mi][ni][r] + bv;
      }
    }
}

// ---------- LSTM scan — hybrid: block-cooperative staging + padded flag stores ----------
// 32 blocks x 256 threads; 4 groups x 8 blocks. U in VGPRs/AGPRs (64KB/wave).
// h slot (g,t) = [32 tiles][16 rows][16 cols] bf16 (tile p = wave p's 16 h-cols).
// Producer per step: gates -> wave-private LDS patch (lgkmcnt wait only) ->
//   wave's contiguous 512 B u64 relaxed-agent store -> ONE __syncthreads
//   (drains vmcnt for all threads) -> tid0 padded flag STORE (no RMW).
// Consumer: poll 8 block-flags in one instruction (lane&7 -> 8 sectors,
//   __all ballot) -> block-cooperative stage of 16 KB (8 dense u64/thread)
//   into LDS -> barrier -> MFMA fragment reads.
#define T_STEPS 512
__global__ __launch_bounds__(256, 1) void lstm_scan(
    const u16* __restrict__ xp,     // [64, 512, 2048] bf16
    const u16* __restrict__ UT,     // [2048, 512] bf16
    u16* __restrict__ hT_all,       // [4][512][32][16][16] bf16 (blocked hidden seq)
    u32* __restrict__ bar,          // [4][8] flags, padded x16 (64 B each)
    float* __restrict__ out_hT,     // [64,512] f32
    float* __restrict__ out_cT) {   // [64,512] f32
  const int bi = blockIdx.x;
  const int g = (bi & 7) >> 1;
  const int wgi = ((bi & 1) << 2) | (bi >> 3);
  const int tid = threadIdx.x;
  const int wave = tid >> 6;
  const int lane = tid & 63;
  const int n = lane & 15;
  const int q4 = lane >> 4;
  const int cb = wgi * 64 + wave * 16;   // wave's h-col base
  const int p = wgi * 4 + wave;          // tile index in group, 0..31

  __shared__ __align__(16) u16 hls[16 * 520];  // staged h_{t-1}, row-major +pad
  __shared__ __align__(8) u16 hstw[4 * 256];   // per-wave 16x16 transpose patch
  u16* hp = hstw + wave * 256;

  // Preload U fragments (B-operand layout)
  bf16x8 u[4][16];
#pragma unroll
  for (int qg = 0; qg < 4; ++qg) {
    const u16* up = UT + (size_t)(qg * 512 + cb + n) * 512;
#pragma unroll
    for (int kt = 0; kt < 16; ++kt)
      u[qg][kt] = *(const bf16x8*)(up + kt * 32 + q4 * 8);
  }

  float cst[4] = {0.f, 0.f, 0.f, 0.f};
  const u16* xp_base = xp + (size_t)(g * 16) * T_STEPS * 2048;
  u32* myflag = bar + (g * 8 + wgi) * 16;
  const u32* pollp = bar + (g * 8 + (lane & 7)) * 16;

#pragma unroll 1
  for (int t = 0; t < T_STEPS; ++t) {
    // xp loads: independent of h_{t-1}; issue before the wait
    float xpv[4][4];
#pragma unroll
    for (int qg = 0; qg < 4; ++qg)
#pragma unroll
      for (int r = 0; r < 4; ++r)
        xpv[qg][r] = bf2f(xp_base[((size_t)(q4 * 4 + r) * T_STEPS + t) * 2048
                                  + qg * 512 + cb + n]);
    __asm__ volatile("" ::: "memory");

    floatx4 acc[4] = {};
    if (t > 0) {
      const u32 tv = (u32)t;
      for (;;) {  // all 8 block flags of this group >= t (8 sector reqs/instr)
        u32 v = __hip_atomic_load(pollp, __ATOMIC_RELAXED, __HIP_MEMORY_SCOPE_AGENT);
        if (__all((int)(v >= tv))) break;
      }
      __asm__ volatile("" ::: "memory");

      // block-cooperative stage of slot t-1: 2048 u64 over 256 threads (dense)
      const u64* hsrc = (const u64*)(hT_all) + (size_t)(g * T_STEPS + (t - 1)) * 2048;
#pragma unroll
      for (int it = 0; it < 8; ++it) {
        int idx = it * 256 + tid;          // u64 index 0..2047
        u64 v = __hip_atomic_load(hsrc + idx, __ATOMIC_RELAXED, __HIP_MEMORY_SCOPE_AGENT);
        int tile = idx >> 6, w = idx & 63;           // blocked: [tile][row][col]
        *(u64*)(hls + (w >> 2) * 520 + tile * 16 + (w & 3) * 4) = v;
      }
      __syncthreads();
#pragma unroll
      for (int kt = 0; kt < 16; ++kt) {
        bf16x8 a = *(const bf16x8*)(hls + n * 520 + kt * 32 + q4 * 8);
        acc[0] = __builtin_amdgcn_mfma_f32_16x16x32_bf16(a, u[0][kt], acc[0], 0, 0, 0);
        acc[1] = __builtin_amdgcn_mfma_f32_16x16x32_bf16(a, u[1][kt], acc[1], 0, 0, 0);
        acc[2] = __builtin_amdgcn_mfma_f32_16x16x32_bf16(a, u[2][kt], acc[2], 0, 0, 0);
        acc[3] = __builtin_amdgcn_mfma_f32_16x16x32_bf16(a, u[3][kt], acc[3], 0, 0, 0);
      }
    }

    // gates + state update (C-layout: row=q4*4+r, col=n within wave tile)
#pragma unroll
    for (int r = 0; r < 4; ++r) {
      float gi = sigm(acc[0][r] + xpv[0][r]);
      float gf = sigm(acc[1][r] + xpv[1][r]);
      float gg = tanh_f(acc[2][r] + xpv[2][r]);
      float go = sigm(acc[3][r] + xpv[3][r]);
      float cn = gf * cst[r] + gi * gg;
      cst[r] = cn;
      float hv = go * tanh_f(cn);
      int row = q4 * 4 + r;
      hp[row * 16 + n] = f2bf(hv);    // wave-private LDS transpose patch
      if (t == T_STEPS - 1) {
        out_hT[(g * 16 + row) * 512 + cb + n] = hv;
        out_cT[(g * 16 + row) * 512 + cb + n] = cn;
      }
    }
    __asm__ volatile("s_waitcnt lgkmcnt(0)" ::: "memory"); // patch visible wave-wide

    // store own 16x16 tile: 64 lanes x u64 = 512 B contiguous, relaxed agent
    {
      u64 v = *(const u64*)(hp + (lane >> 2) * 16 + (lane & 3) * 4);
      u64* hdst = (u64*)(hT_all) + (size_t)(g * T_STEPS + t) * 2048 + p * 64 + lane;
      __hip_atomic_store(hdst, v, __ATOMIC_RELAXED, __HIP_MEMORY_SCOPE_AGENT);
    }
    __syncthreads();   // drains vmcnt(0) per thread -> all 4 waves' h stores visible
    if (tid == 0)
      __hip_atomic_store(myflag, (u32)(t + 1),
                         __ATOMIC_RELAXED, __HIP_MEMORY_SCOPE_AGENT);
  }
}

// ---------- launch ----------
extern "C" void kernel_launch(void* const* d_in, const int* in_sizes, int n_in,
                              void* d_out, int out_size, void* d_ws, size_t ws_size,
                              hipStream_t stream) {
  (void)in_sizes; (void)n_in; (void)out_size; (void)ws_size;
  const float* x    = (const float*)d_in[0]; // [64,512,256] f32
  const float* W    = (const float*)d_in[1]; // [256,2048] f32
  const float* U    = (const float*)d_in[2]; // [512,2048] f32
  const float* bias = (const float*)d_in[3]; // [2048] f32
  const float* Wl   = (const float*)d_in[4]; // [512,256] f32
  const float* bl   = (const float*)d_in[5]; // [256] f32
  float* out = (float*)d_out;                // [64,512,256] ++ hT[64,512] ++ cT[64,512]
  char* ws = (char*)d_ws;

  u16* xp     = (u16*)(ws + 0);            // 134,217,728 B
  u16* UT     = (u16*)(ws + 134217728);    //   2,097,152 B
  u16* WT     = (u16*)(ws + 136314880);    //   1,048,576 B
  u16* WlT    = (u16*)(ws + 137363456);    //     262,144 B
  u16* hT_all = (u16*)(ws + 137625600);    //  33,554,432 B  [4][512][32][16][16]
  u32* bar    = (u32*)(ws + 171180032);    //       2,048 B  [4][8] x16 pad

  hipMemsetAsync(bar, 0, 4 * 8 * 16 * sizeof(u32), stream);

  transpose_f32_bf16<<<dim3(2048 / 32, 256 / 32), dim3(32, 8), 0, stream>>>(W, WT, 256, 2048);
  transpose_f32_bf16<<<dim3(2048 / 32, 512 / 32), dim3(32, 8), 0, stream>>>(U, UT, 512, 2048);
  transpose_f32_bf16<<<dim3(256 / 32, 512 / 32), dim3(32, 8), 0, stream>>>(Wl, WlT, 512, 256);

  // x_proj = x @ W + bias : [32768,256] x [256,2048] -> bf16
  gemm_a32_bt<<<dim3(2048 / 64, 32768 / 64), 256, 0, stream>>>(x, WT, bias, xp, 32768, 2048, 256);

  // sequential LSTM scan (writes hT_all in blocked [g][t][tile][row][col] layout)
  lstm_scan<<<32, 256, 0, stream>>>(xp, UT, hT_all, bar,
                                    out + 8388608, out + 8421376);

  // out = hseq @ Wl + bl, reading blocked layout, remapping output rows
  gemm_bt_f32out_perm<<<dim3(256 / 64, 32768 / 64), 256, 0, stream>>>(
      hT_all, WlT, bl, out, 32768, 256, 512);
}

// Round 8
// 1476.120 us; speedup vs baseline: 2.6696x; 1.6636x over previous
//
#include <hip/hip_runtime.h>
#include <stdint.h>

typedef uint16_t u16;
typedef uint32_t u32;
typedef unsigned long long u64;
typedef __attribute__((ext_vector_type(8))) __bf16 bf16x8;
typedef __attribute__((ext_vector_type(8))) short short8;
typedef __attribute__((ext_vector_type(4))) float floatx4;

// ---------- helpers ----------
__device__ __forceinline__ float bf2f(u16 u) {
  union { u32 i; float f; } v; v.i = ((u32)u) << 16; return v.f;
}
__device__ __forceinline__ u16 f2bf(float f) {
  union { float f; u32 i; } v; v.f = f;
  u32 i = v.i;
  return (u16)((i + 0x7FFFu + ((i >> 16) & 1u)) >> 16); // RTNE
}
__device__ __forceinline__ float sigm(float x) { return 1.f / (1.f + __expf(-x)); }
__device__ __forceinline__ float tanh_f(float x) {
  x = fminf(15.f, fmaxf(-15.f, x));
  float e = __expf(2.f * x);
  return (e - 1.f) / (e + 1.f);
}

// ---------- fp32 -> bf16 transpose: src[R][C] f32 -> dst[C][R] bf16 ----------
__global__ void transpose_f32_bf16(const float* __restrict__ src, u16* __restrict__ dst,
                                   int R, int C) {
  __shared__ u16 tile[32][33];
  int x = blockIdx.x * 32 + threadIdx.x;
#pragma unroll
  for (int j = 0; j < 4; ++j) {
    int y = blockIdx.y * 32 + threadIdx.y + j * 8;
    if (x < C && y < R) tile[threadIdx.y + j * 8][threadIdx.x] = f2bf(src[(size_t)y * C + x]);
  }
  __syncthreads();
  int x2 = blockIdx.y * 32 + threadIdx.x;
#pragma unroll
  for (int j = 0; j < 4; ++j) {
    int y2 = blockIdx.x * 32 + threadIdx.y + j * 8;
    if (x2 < R && y2 < C) dst[(size_t)y2 * R + x2] = tile[threadIdx.x][threadIdx.y + j * 8];
  }
}

// ---------- xp GEMM: C_bf16[M,N] = A_f32[M,K] @ BT_bf16[N,K]^T + bias_f32 ----------
__global__ __launch_bounds__(256) void gemm_a32_bt(
    const float* __restrict__ A, const u16* __restrict__ BT,
    const float* __restrict__ bias, u16* __restrict__ C,
    int M, int N, int K) {
  __shared__ __align__(16) u16 As[64 * 40];
  __shared__ __align__(16) u16 Bs[64 * 40];
  const int tid = threadIdx.x;
  const int wave = tid >> 6, lane = tid & 63;
  const int q4 = lane >> 4, n16 = lane & 15;
  const int mw = (wave >> 1) * 32, nw = (wave & 1) * 32;
  const int m0 = blockIdx.y * 64, n0 = blockIdx.x * 64;
  const int ldrow = tid >> 2, ldseg = (tid & 3) * 8;

  floatx4 acc[2][2] = {};
  for (int k0 = 0; k0 < K; k0 += 32) {
    const float* ap = A + (size_t)(m0 + ldrow) * K + k0 + ldseg;
    floatx4 a0 = *(const floatx4*)ap;
    floatx4 a1 = *(const floatx4*)(ap + 4);
    short8 s;
    s[0] = (short)f2bf(a0[0]); s[1] = (short)f2bf(a0[1]);
    s[2] = (short)f2bf(a0[2]); s[3] = (short)f2bf(a0[3]);
    s[4] = (short)f2bf(a1[0]); s[5] = (short)f2bf(a1[1]);
    s[6] = (short)f2bf(a1[2]); s[7] = (short)f2bf(a1[3]);
    *(short8*)(As + ldrow * 40 + ldseg) = s;
    *(short8*)(Bs + ldrow * 40 + ldseg) =
        *(const short8*)(BT + (size_t)(n0 + ldrow) * K + k0 + ldseg);
    __syncthreads();
#pragma unroll
    for (int mi = 0; mi < 2; ++mi) {
      bf16x8 a = *(const bf16x8*)(As + (mw + mi * 16 + n16) * 40 + q4 * 8);
#pragma unroll
      for (int ni = 0; ni < 2; ++ni) {
        bf16x8 b = *(const bf16x8*)(Bs + (nw + ni * 16 + n16) * 40 + q4 * 8);
        acc[mi][ni] = __builtin_amdgcn_mfma_f32_16x16x32_bf16(a, b, acc[mi][ni], 0, 0, 0);
      }
    }
    __syncthreads();
  }
#pragma unroll
  for (int mi = 0; mi < 2; ++mi)
#pragma unroll
    for (int ni = 0; ni < 2; ++ni) {
      int col = n0 + nw + ni * 16 + n16;
      float bv = bias[col];
#pragma unroll
      for (int r = 0; r < 4; ++r) {
        int m = m0 + mw + mi * 16 + q4 * 4 + r;
        C[(size_t)m * N + col] = f2bf(acc[mi][ni][r] + bv);
      }
    }
}

// ---------- final GEMM over blocked+permuted hidden layout ----------
// A'row m: g=m>>13, t=(m&8191)>>4, r=m&15. Slot (g,t) = [32 tiles][16 r][16 c] u16;
// element k at (k>>4)*256 + r*16 + (k&15). Output row = (g*16+r)*512 + t.
__global__ __launch_bounds__(256) void gemm_bt_f32out_perm(
    const u16* __restrict__ A, const u16* __restrict__ BT,
    const float* __restrict__ bias, float* __restrict__ C,
    int M, int N, int K) {
  __shared__ __align__(16) u16 As[64 * 40];
  __shared__ __align__(16) u16 Bs[64 * 40];
  const int tid = threadIdx.x;
  const int wave = tid >> 6, lane = tid & 63;
  const int q4 = lane >> 4, n16 = lane & 15;
  const int mw = (wave >> 1) * 32, nw = (wave & 1) * 32;
  const int m0 = blockIdx.y * 64, n0 = blockIdx.x * 64;
  const int ldrow = tid >> 2, ldseg = (tid & 3) * 8;

  const int mm = m0 + ldrow;
  const size_t slot = ((size_t)((mm >> 13) * 512 + ((mm & 8191) >> 4))) * 8192
                      + (mm & 15) * 16;

  floatx4 acc[2][2] = {};
  for (int k0 = 0; k0 < K; k0 += 32) {
    int kk = k0 + ldseg;
    *(short8*)(As + ldrow * 40 + ldseg) =
        *(const short8*)(A + slot + (kk >> 4) * 256 + (kk & 15));
    *(short8*)(Bs + ldrow * 40 + ldseg) =
        *(const short8*)(BT + (size_t)(n0 + ldrow) * K + k0 + ldseg);
    __syncthreads();
#pragma unroll
    for (int mi = 0; mi < 2; ++mi) {
      bf16x8 a = *(const bf16x8*)(As + (mw + mi * 16 + n16) * 40 + q4 * 8);
#pragma unroll
      for (int ni = 0; ni < 2; ++ni) {
        bf16x8 b = *(const bf16x8*)(Bs + (nw + ni * 16 + n16) * 40 + q4 * 8);
        acc[mi][ni] = __builtin_amdgcn_mfma_f32_16x16x32_bf16(a, b, acc[mi][ni], 0, 0, 0);
      }
    }
    __syncthreads();
  }
#pragma unroll
  for (int mi = 0; mi < 2; ++mi)
#pragma unroll
    for (int ni = 0; ni < 2; ++ni) {
      int col = n0 + nw + ni * 16 + n16;
      float bv = bias[col];
#pragma unroll
      for (int r = 0; r < 4; ++r) {
        int m = m0 + mw + mi * 16 + q4 * 4 + r;
        int orow = ((m >> 13) * 16 + (m & 15)) * 512 + ((m & 8191) >> 4);
        C[(size_t)orow * N + col] = acc[mi][ni][r] + bv;
      }
    }
}

// ---------- LSTM scan — flagless: sentinel-poll on the h data itself ----------
// 32 blocks x 256 threads; 4 groups x 8 blocks. U in VGPRs (64KB/wave).
// h slot (g,t) = [32 tiles][16 rows][16 cols] bf16, pre-filled 0xFF (sentinel).
// h = sigm*tanh is finite -> bf16 0xFFFF (NaN) is impossible -> a u64 of h data
// can never equal ~0. Producer: gates -> LDS patch -> 512 B contiguous relaxed
// u64 stores (NO drain, NO flag, NO barrier). Consumer: sweep-poll own 8
// staging u64s (one RT per sweep) until all != sentinel -- the detecting load
// IS the data -- then parity-double-buffered LDS stage + one __syncthreads.
#define T_STEPS 512
#define HLSZ (16 * 520)
__global__ __launch_bounds__(256, 1) void lstm_scan(
    const u16* __restrict__ xp,     // [64, 512, 2048] bf16
    const u16* __restrict__ UT,     // [2048, 512] bf16
    u16* __restrict__ hT_all,       // [4][512][32][16][16] bf16, sentinel-filled
    float* __restrict__ out_hT,     // [64,512] f32
    float* __restrict__ out_cT) {   // [64,512] f32
  const int bi = blockIdx.x;
  const int g = (bi & 7) >> 1;
  const int wgi = ((bi & 1) << 2) | (bi >> 3);
  const int tid = threadIdx.x;
  const int wave = tid >> 6;
  const int lane = tid & 63;
  const int n = lane & 15;
  const int q4 = lane >> 4;
  const int cb = wgi * 64 + wave * 16;   // wave's h-col base
  const int p = wgi * 4 + wave;          // tile index in group, 0..31

  __shared__ __align__(16) u16 hls[2 * HLSZ];  // parity-double-buffered stage
  __shared__ __align__(8) u16 hstw[4 * 256];   // per-wave 16x16 transpose patch
  u16* hp = hstw + wave * 256;

  // Preload U fragments (B-operand layout)
  bf16x8 u[4][16];
#pragma unroll
  for (int qg = 0; qg < 4; ++qg) {
    const u16* up = UT + (size_t)(qg * 512 + cb + n) * 512;
#pragma unroll
    for (int kt = 0; kt < 16; ++kt)
      u[qg][kt] = *(const bf16x8*)(up + kt * 32 + q4 * 8);
  }

  float cst[4] = {0.f, 0.f, 0.f, 0.f};
  const u16* xp_base = xp + (size_t)(g * 16) * T_STEPS * 2048;

#pragma unroll 1
  for (int t = 0; t < T_STEPS; ++t) {
    // xp loads: independent of h_{t-1}; issue before the wait
    float xpv[4][4];
#pragma unroll
    for (int qg = 0; qg < 4; ++qg)
#pragma unroll
      for (int r = 0; r < 4; ++r)
        xpv[qg][r] = bf2f(xp_base[((size_t)(q4 * 4 + r) * T_STEPS + t) * 2048
                                  + qg * 512 + cb + n]);
    __asm__ volatile("" ::: "memory");

    floatx4 acc[4] = {};
    if (t > 0) {
      // sweep-poll own 8 staging u64s of slot t-1; detecting load IS the data
      const u64* hsrc = (const u64*)(hT_all) + (size_t)(g * T_STEPS + (t - 1)) * 2048;
      u64 v[8];
      for (;;) {
#pragma unroll
        for (int it = 0; it < 8; ++it)
          v[it] = __hip_atomic_load(hsrc + it * 256 + tid,
                                    __ATOMIC_RELAXED, __HIP_MEMORY_SCOPE_AGENT);
        bool ok = true;
#pragma unroll
        for (int it = 0; it < 8; ++it) ok &= (v[it] != ~0ull);
        if (ok) break;
      }
      __asm__ volatile("" ::: "memory");

      u16* buf = hls + ((t - 1) & 1) * HLSZ;
#pragma unroll
      for (int it = 0; it < 8; ++it) {
        int idx = it * 256 + tid;          // u64 index 0..2047
        int tile = idx >> 6, w = idx & 63; // blocked: [tile][row][col]
        *(u64*)(buf + (w >> 2) * 520 + tile * 16 + (w & 3) * 4) = v[it];
      }
      __syncthreads();   // stage complete, block-wide
#pragma unroll
      for (int kt = 0; kt < 16; ++kt) {
        bf16x8 a = *(const bf16x8*)(buf + n * 520 + kt * 32 + q4 * 8);
        acc[0] = __builtin_amdgcn_mfma_f32_16x16x32_bf16(a, u[0][kt], acc[0], 0, 0, 0);
        acc[1] = __builtin_amdgcn_mfma_f32_16x16x32_bf16(a, u[1][kt], acc[1], 0, 0, 0);
        acc[2] = __builtin_amdgcn_mfma_f32_16x16x32_bf16(a, u[2][kt], acc[2], 0, 0, 0);
        acc[3] = __builtin_amdgcn_mfma_f32_16x16x32_bf16(a, u[3][kt], acc[3], 0, 0, 0);
      }
    }

    // gates + state update (C-layout: row=q4*4+r, col=n within wave tile)
#pragma unroll
    for (int r = 0; r < 4; ++r) {
      float gi = sigm(acc[0][r] + xpv[0][r]);
      float gf = sigm(acc[1][r] + xpv[1][r]);
      float gg = tanh_f(acc[2][r] + xpv[2][r]);
      float go = sigm(acc[3][r] + xpv[3][r]);
      float cn = gf * cst[r] + gi * gg;
      cst[r] = cn;
      float hv = go * tanh_f(cn);
      int row = q4 * 4 + r;
      hp[row * 16 + n] = f2bf(hv);    // wave-private LDS transpose patch
      if (t == T_STEPS - 1) {
        out_hT[(g * 16 + row) * 512 + cb + n] = hv;
        out_cT[(g * 16 + row) * 512 + cb + n] = cn;
      }
    }
    __asm__ volatile("s_waitcnt lgkmcnt(0)" ::: "memory"); // patch visible wave-wide

    // store own 16x16 tile: 64 lanes x u64 = 512 B contiguous, relaxed agent.
    // No drain, no flag -- consumers detect via sentinel disappearance.
    {
      u64 v = *(const u64*)(hp + (lane >> 2) * 16 + (lane & 3) * 4);
      u64* hdst = (u64*)(hT_all) + (size_t)(g * T_STEPS + t) * 2048 + p * 64 + lane;
      __hip_atomic_store(hdst, v, __ATOMIC_RELAXED, __HIP_MEMORY_SCOPE_AGENT);
    }
  }
}

// ---------- launch ----------
extern "C" void kernel_launch(void* const* d_in, const int* in_sizes, int n_in,
                              void* d_out, int out_size, void* d_ws, size_t ws_size,
                              hipStream_t stream) {
  (void)in_sizes; (void)n_in; (void)out_size; (void)ws_size;
  const float* x    = (const float*)d_in[0]; // [64,512,256] f32
  const float* W    = (const float*)d_in[1]; // [256,2048] f32
  const float* U    = (const float*)d_in[2]; // [512,2048] f32
  const float* bias = (const float*)d_in[3]; // [2048] f32
  const float* Wl   = (const float*)d_in[4]; // [512,256] f32
  const float* bl   = (const float*)d_in[5]; // [256] f32
  float* out = (float*)d_out;                // [64,512,256] ++ hT[64,512] ++ cT[64,512]
  char* ws = (char*)d_ws;

  u16* xp     = (u16*)(ws + 0);            // 134,217,728 B
  u16* UT     = (u16*)(ws + 134217728);    //   2,097,152 B
  u16* WT     = (u16*)(ws + 136314880);    //   1,048,576 B
  u16* WlT    = (u16*)(ws + 137363456);    //     262,144 B
  u16* hT_all = (u16*)(ws + 137625600);    //  33,554,432 B  [4][512][32][16][16]

  // sentinel-fill h slots (0xFFFF bf16 = NaN, impossible as an h value)
  hipMemsetAsync(hT_all, 0xFF, 33554432, stream);

  transpose_f32_bf16<<<dim3(2048 / 32, 256 / 32), dim3(32, 8), 0, stream>>>(W, WT, 256, 2048);
  transpose_f32_bf16<<<dim3(2048 / 32, 512 / 32), dim3(32, 8), 0, stream>>>(U, UT, 512, 2048);
  transpose_f32_bf16<<<dim3(256 / 32, 512 / 32), dim3(32, 8), 0, stream>>>(Wl, WlT, 512, 256);

  // x_proj = x @ W + bias : [32768,256] x [256,2048] -> bf16
  gemm_a32_bt<<<dim3(2048 / 64, 32768 / 64), 256, 0, stream>>>(x, WT, bias, xp, 32768, 2048, 256);

  // sequential LSTM scan (writes hT_all in blocked [g][t][tile][row][col] layout)
  lstm_scan<<<32, 256, 0, stream>>>(xp, UT, hT_all,
                                    out + 8388608, out + 8421376);

  // out = hseq @ Wl + bl, reading blocked layout, remapping output rows
  gemm_bt_f32out_perm<<<dim3(256 / 64, 32768 / 64), 256, 0, stream>>>(
      hT_all, WlT, bl, out, 32768, 256, 512);
}